// Round 14
// baseline (222.257 us; speedup 1.0000x reference)
//
#include <hip/hip_runtime.h>
#include <math.h>

#define T_TOK 8192
#define HDIM 4096
#define NSLOT 128
#define KRET 4
#define TOPK 2048
#define ALPHA 0.1f
#define SEG 16       // token segments
#define CH 64        // d-chunks of 64 floats

// ---------------- Kernel 1: per-token importance (+ zero rank) ----------------
__global__ __launch_bounds__(256) void importance_kernel(
    const float* __restrict__ h, const float* __restrict__ attn,
    const float* __restrict__ W, const float* __restrict__ b,
    float* __restrict__ imp, int* __restrict__ rank)
{
    const int wid  = threadIdx.x >> 6;
    const int lane = threadIdx.x & 63;
    const int t = blockIdx.x * 4 + wid;
    const float4* hv = reinterpret_cast<const float4*>(h + (size_t)t * HDIM);
    const float4* Wv = reinterpret_cast<const float4*>(W);
    float sumsq = 0.f, dot = 0.f;
    #pragma unroll 4
    for (int i = 0; i < 16; i++) {
        float4 x = hv[lane + i * 64];
        float4 w = Wv[lane + i * 64];
        sumsq += x.x * x.x + x.y * x.y + x.z * x.z + x.w * x.w;
        dot   += x.x * w.x + x.y * w.y + x.z * w.z + x.w * w.w;
    }
    #pragma unroll
    for (int off = 32; off > 0; off >>= 1) {
        sumsq += __shfl_down(sumsq, off);
        dot   += __shfl_down(dot, off);
    }
    if (lane == 0) {
        float mag = sqrtf(sumsq);
        float ent = 0.f;
        #pragma unroll
        for (int k = 0; k < KRET; k++) {
            float a = attn[t * KRET + k];
            ent -= a * logf(a + 1e-8f);
        }
        float surprise = ent / logf(4.0f);
        float score = dot + b[0];
        float sig = 1.0f / (1.0f + expf(-score));
        imp[t] = mag * (1.0f + surprise) + sig;
        rank[t] = 0;  // zero for rank_kernel (stream-ordered, replay-safe)
    }
}

// ---------------- Kernel 2: partial rank count, 2-D grid (R4, proven) --------
__global__ __launch_bounds__(256) void rank_kernel(
    const float* __restrict__ imp, int* __restrict__ rank)
{
    const int cb = blockIdx.x & 31;   // candidate block
    const int sl = blockIdx.x >> 5;   // compare slice
    __shared__ float tile[256];
    const int base = sl * 256;
    tile[threadIdx.x] = imp[base + threadIdx.x];
    __syncthreads();
    const int t = cb * 256 + threadIdx.x;
    const float mine = imp[t];
    int r = 0;
    #pragma unroll 8
    for (int i = 0; i < 256; i++) {
        float v = tile[i];
        int s = base + i;
        // jax.lax.top_k tie-break: higher value first, then lower index
        r += (v > mine) || (v == mine && s < t);
    }
    if (r) atomicAdd(&rank[t], r);
}

// ---------------- Kernel 3: scatter-v2 — LDS-atomic partial sums -------------
// grid = 16 segs x 64 chunks = 1024 blocks, 256 thr (4 waves). 34.5 KB LDS ->
// 4 blocks/CU -> 16 waves/CU. Each selected h-row read ONCE (32 MB total).
// ds_add_f32 accumulation: lanes hit consecutive addresses (2/bank = free),
// consecutive tokens hit different slots -> RMWs pipeline.
__global__ __launch_bounds__(256) void scatter_kernel(
    const float* __restrict__ h, const int* __restrict__ rank,
    const int* __restrict__ si, float* __restrict__ partial,
    int* __restrict__ pcnt)
{
    const int chunk = blockIdx.x & 63;
    const int seg   = blockIdx.x >> 6;   // 0..15
    const int tid = threadIdx.x;
    const int w = tid >> 6, lane = tid & 63;

    __shared__ float s_acc[NSLOT * 64];  // 32 KB
    __shared__ int   s_tok[4][128];      // per-wave selected token lists
    __shared__ int   s_cnt[NSLOT];

    for (int i = tid; i < NSLOT * 64; i += 256) s_acc[i] = 0.f;
    if (tid < NSLOT) s_cnt[tid] = 0;
    __syncthreads();

    // Phase A (lane = token): ballot-compact this wave's 128-token range
    const int tbase = seg * 512 + w * 128;
    int n = 0;
    #pragma unroll
    for (int it = 0; it < 2; it++) {
        const int t = tbase + it * 64 + lane;
        bool sel = rank[t] < TOPK;
        unsigned long long bal = __ballot(sel);
        if (sel) {
            int pos = n + (int)__popcll(bal & ((1ull << lane) - 1ull));
            s_tok[w][pos] = t;
        }
        n += (int)__popcll(bal);
    }
    // (own-wave LDS read-after-write; no cross-wave consumer of s_tok)

    // Phase B (lane = d-element): read each row once, ds_add into slot rows
    const int4* si4 = reinterpret_cast<const int4*>(si);
    const float* hcol = h + chunk * 64 + lane;
    for (int i = 0; i < n; i++) {
        const int t = s_tok[w][i];
        const int4 s4 = si4[t];
        const float x = hcol[(size_t)t * HDIM];
        bool dy = (s4.y != s4.x);
        bool dz = (s4.z != s4.x) && (s4.z != s4.y);
        bool dw = (s4.w != s4.x) && (s4.w != s4.y) && (s4.w != s4.z);
        atomicAdd(&s_acc[s4.x * 64 + lane], x);
        if (dy) atomicAdd(&s_acc[s4.y * 64 + lane], x);
        if (dz) atomicAdd(&s_acc[s4.z * 64 + lane], x);
        if (dw) atomicAdd(&s_acc[s4.w * 64 + lane], x);
    }

    // counts: only the 16 chunk==0 blocks, lane-parallel over tokens
    if (chunk == 0) {
        for (int i = lane; i < n; i += 64) {
            const int t = s_tok[w][i];
            const int4 s4 = si4[t];
            bool dy = (s4.y != s4.x);
            bool dz = (s4.z != s4.x) && (s4.z != s4.y);
            bool dw = (s4.w != s4.x) && (s4.w != s4.y) && (s4.w != s4.z);
            atomicAdd(&s_cnt[s4.x], 1);
            if (dy) atomicAdd(&s_cnt[s4.y], 1);
            if (dz) atomicAdd(&s_cnt[s4.z], 1);
            if (dw) atomicAdd(&s_cnt[s4.w], 1);
        }
    }
    __syncthreads();

    // write partial[seg][slot][chunk*64 .. +64]
    const float4* a4 = reinterpret_cast<const float4*>(s_acc);
    for (int i = tid; i < NSLOT * 16; i += 256) {   // 2048 float4s
        const int slot = i >> 4;
        const int d4 = i & 15;
        reinterpret_cast<float4*>(
            partial + ((size_t)(seg * NSLOT + slot)) * HDIM + chunk * 64)[d4] = a4[i];
    }
    if (chunk == 0 && tid < NSLOT) pcnt[seg * NSLOT + tid] = s_cnt[tid];
}

// ---------------- Kernel 4: combine partials + EMA + write output ----------
__global__ __launch_bounds__(256) void combine_kernel(
    const float* __restrict__ partial, const int* __restrict__ pcnt,
    const float* __restrict__ mem, float* __restrict__ out)
{
    const int slot = blockIdx.x >> 2;
    const int q = blockIdx.x & 3;
    const int dbase = q * 1024 + threadIdx.x * 4;

    int cnt = 0;
    float4 s = make_float4(0.f, 0.f, 0.f, 0.f);
    #pragma unroll
    for (int seg = 0; seg < SEG; seg++) {
        cnt += pcnt[seg * NSLOT + slot];
        float4 p = *reinterpret_cast<const float4*>(
            partial + ((size_t)(seg * NSLOT + slot)) * HDIM + dbase);
        s.x += p.x; s.y += p.y; s.z += p.z; s.w += p.w;
    }

    const size_t o = (size_t)slot * HDIM + dbase;
    float4 cur = *reinterpret_cast<const float4*>(mem + o);
    float4 r;
    if (cnt > 0) {
        float inv = 1.0f / (float)cnt;
        r.x = ALPHA * (s.x * inv) + (1.f - ALPHA) * cur.x;
        r.y = ALPHA * (s.y * inv) + (1.f - ALPHA) * cur.y;
        r.z = ALPHA * (s.z * inv) + (1.f - ALPHA) * cur.z;
        r.w = ALPHA * (s.w * inv) + (1.f - ALPHA) * cur.w;
    } else {
        r = cur;
    }
    *reinterpret_cast<float4*>(out + o) = r;
}

extern "C" void kernel_launch(void* const* d_in, const int* in_sizes, int n_in,
                              void* d_out, int out_size, void* d_ws, size_t ws_size,
                              hipStream_t stream) {
    const float* h    = (const float*)d_in[0];  // [8192, 4096]
    const float* attn = (const float*)d_in[1];  // [8192, 4]
    const int*   si   = (const int*)d_in[2];    // [8192, 4]
    const float* mem  = (const float*)d_in[3];  // [1, 128, 4096]
    const float* W    = (const float*)d_in[4];  // [1, 4096]
    const float* b    = (const float*)d_in[5];  // [1]
    float* out = (float*)d_out;                 // [1, 128, 4096]

    char* ws = (char*)d_ws;
    float* imp     = (float*)(ws);             // 8192 f32
    int*   rank    = (int*)(ws + 32768);       // 8192 i32
    int*   pcnt    = (int*)(ws + 65536);       // 16 x 128 i32
    float* partial = (float*)(ws + 2097152);   // 16 x 128 x 4096 f32 (32 MB)

    importance_kernel<<<T_TOK / 4, 256, 0, stream>>>(h, attn, W, b, imp, rank);
    rank_kernel<<<1024, 256, 0, stream>>>(imp, rank);
    scatter_kernel<<<SEG * CH, 256, 0, stream>>>(h, rank, si, partial, pcnt);
    combine_kernel<<<NSLOT * 4, 256, 0, stream>>>(partial, pcnt, mem, out);
}

// Round 15
// 108.109 us; speedup vs baseline: 2.0559x; 2.0559x over previous
//
#include <hip/hip_runtime.h>
#include <math.h>

#define T_TOK 8192
#define HDIM 4096
#define NSLOT 128
#define KRET 4
#define TOPK 2048
#define KSEL 2048

typedef __attribute__((ext_vector_type(8))) short short8v;   // 8 bf16 (4 VGPRs)
typedef __attribute__((ext_vector_type(4))) float floatx4;   // MFMA acc

__device__ __forceinline__ ushort f2bf(float f) {
    unsigned u = __float_as_uint(f);
    unsigned r = (u + 0x7FFFu + ((u >> 16) & 1u)) >> 16;   // RNE
    return (ushort)r;
}

// ---------------- Kernel 1: per-token importance (+ zero rank) ----------------
__global__ __launch_bounds__(256) void importance_kernel(
    const float* __restrict__ h, const float* __restrict__ attn,
    const float* __restrict__ W, const float* __restrict__ b,
    float* __restrict__ imp, int* __restrict__ rank)
{
    const int wid  = threadIdx.x >> 6;
    const int lane = threadIdx.x & 63;
    const int t = blockIdx.x * 4 + wid;
    const float4* hv = reinterpret_cast<const float4*>(h + (size_t)t * HDIM);
    const float4* Wv = reinterpret_cast<const float4*>(W);
    float sumsq = 0.f, dot = 0.f;
    #pragma unroll 4
    for (int i = 0; i < 16; i++) {
        float4 x = hv[lane + i * 64];
        float4 w = Wv[lane + i * 64];
        sumsq += x.x * x.x + x.y * x.y + x.z * x.z + x.w * x.w;
        dot   += x.x * w.x + x.y * w.y + x.z * w.z + x.w * w.w;
    }
    #pragma unroll
    for (int off = 32; off > 0; off >>= 1) {
        sumsq += __shfl_down(sumsq, off);
        dot   += __shfl_down(dot, off);
    }
    if (lane == 0) {
        float mag = sqrtf(sumsq);
        float ent = 0.f;
        #pragma unroll
        for (int k = 0; k < KRET; k++) {
            float a = attn[t * KRET + k];
            ent -= a * logf(a + 1e-8f);
        }
        float surprise = ent / logf(4.0f);
        float score = dot + b[0];
        float sig = 1.0f / (1.0f + expf(-score));
        imp[t] = mag * (1.0f + surprise) + sig;
        rank[t] = 0;  // zero for rank_kernel (stream-ordered, replay-safe)
    }
}

// ---------------- Kernel 2: partial rank count (R4, proven) + zero counts ----
__global__ __launch_bounds__(256) void rank_kernel(
    const float* __restrict__ imp, int* __restrict__ rank,
    int* __restrict__ counts)
{
    if (blockIdx.x == 0 && threadIdx.x < NSLOT) counts[threadIdx.x] = 0;
    const int cb = blockIdx.x & 31;   // candidate block
    const int sl = blockIdx.x >> 5;   // compare slice
    __shared__ float tile[256];
    const int base = sl * 256;
    tile[threadIdx.x] = imp[base + threadIdx.x];
    __syncthreads();
    const int t = cb * 256 + threadIdx.x;
    const float mine = imp[t];
    int r = 0;
    #pragma unroll 8
    for (int i = 0; i < 256; i++) {
        float v = tile[i];
        int s = base + i;
        // jax.lax.top_k tie-break: higher value first, then lower index
        r += (v > mine) || (v == mine && s < t);
    }
    if (r) atomicAdd(&rank[t], r);
}

// ---------------- Kernel 3: compact selected rows -> bf16 Hsel + M_T + counts
// 256 blocks x 32 tokens. Deterministic: positions = # selected t' < t
// (redundant per-block rank scan); int atomics only for counts.
__global__ __launch_bounds__(256) void gather_kernel(
    const float* __restrict__ h, const int* __restrict__ rank,
    const int* __restrict__ si, ushort* __restrict__ Hsel,
    ushort* __restrict__ M_T, int* __restrict__ counts)
{
    const int bid = blockIdx.x;
    const int tid = threadIdx.x;
    const int t0 = bid * 32;

    __shared__ int s_red[4];
    __shared__ int s_flag[32], s_pos[32], s_tok[32];
    __shared__ int s_base, s_n;

    // 1. base position = # selected tokens before t0
    int c = 0;
    for (int t = tid; t < t0; t += 256) c += (rank[t] < TOPK) ? 1 : 0;
    #pragma unroll
    for (int off = 32; off > 0; off >>= 1) c += __shfl_down(c, off);
    if ((tid & 63) == 0) s_red[tid >> 6] = c;
    if (tid < 32) s_flag[tid] = (rank[t0 + tid] < TOPK) ? 1 : 0;
    __syncthreads();
    if (tid == 0) {
        s_base = s_red[0] + s_red[1] + s_red[2] + s_red[3];
        int p = 0;
        for (int j = 0; j < 32; j++) { s_pos[j] = p; p += s_flag[j]; }
        s_n = p;
    }
    __syncthreads();
    const int n = s_n, base = s_base;
    if (tid < 32 && s_flag[tid]) s_tok[s_pos[tid]] = t0 + tid;
    __syncthreads();

    // 2. zero this block's M_T columns [base, base+n) across all 128 slot rows
    for (int i = tid; i < NSLOT * n; i += 256) {
        int srow = i / n;
        int ci = i - srow * n;
        M_T[(size_t)srow * KSEL + base + ci] = 0;
    }

    // 3. copy selected rows f32 -> bf16 (each row read ONCE)
    for (int i = 0; i < n; i++) {
        const int t = s_tok[i];
        const float4* src = reinterpret_cast<const float4*>(h + (size_t)t * HDIM) + tid * 4;
        ushort us[16];
        #pragma unroll
        for (int q = 0; q < 4; q++) {
            float4 x = src[q];
            us[q * 4 + 0] = f2bf(x.x); us[q * 4 + 1] = f2bf(x.y);
            us[q * 4 + 2] = f2bf(x.z); us[q * 4 + 3] = f2bf(x.w);
        }
        uint4* dst = reinterpret_cast<uint4*>(Hsel + (size_t)(base + i) * HDIM) + tid * 2;
        dst[0] = *reinterpret_cast<const uint4*>(&us[0]);
        dst[1] = *reinterpret_cast<const uint4*>(&us[8]);
    }
    __syncthreads();

    // 4. membership ones + counts (dedup within token)
    if (tid < 32 && s_flag[tid]) {
        const int p = base + s_pos[tid];
        int4 s4 = reinterpret_cast<const int4*>(si)[t0 + tid];
        bool dy = (s4.y != s4.x);
        bool dz = (s4.z != s4.x) && (s4.z != s4.y);
        bool dw = (s4.w != s4.x) && (s4.w != s4.y) && (s4.w != s4.z);
        const ushort ONE = 0x3F80;  // bf16 1.0
        M_T[(size_t)s4.x * KSEL + p] = ONE; atomicAdd(&counts[s4.x], 1);
        if (dy) { M_T[(size_t)s4.y * KSEL + p] = ONE; atomicAdd(&counts[s4.y], 1); }
        if (dz) { M_T[(size_t)s4.z * KSEL + p] = ONE; atomicAdd(&counts[s4.z], 1); }
        if (dw) { M_T[(size_t)s4.w * KSEL + p] = ONE; atomicAdd(&counts[s4.w], 1); }
    }
}

// ---------------- Kernel 4: MFMA einsum sums = M_T @ Hsel, EMA epilogue ------
// C[128 slots][4096 d]. 256 blocks: sg(2 slot-halves) x db(128 d-blocks of 32).
// Per block: 4 waves x one 16-slot tile x two 16-d tiles; K-loop 2048/32.
// mfma_f32_16x16x32_bf16: A row=lane&15, k=8*(lane>>4)+i (M_T rows, global);
// B k=8*(lane>>4)+i, col=lane&15 (LDS, staged transposed [d][k]);
// C col=lane&15 (d), row=(lane>>4)*4+reg (slot)  [m89-verified layouts].
__global__ __launch_bounds__(256) void einsum_kernel(
    const ushort* __restrict__ Hsel, const ushort* __restrict__ M_T,
    const int* __restrict__ counts, const float* __restrict__ mem,
    float* __restrict__ out)
{
    const int bid = blockIdx.x;
    const int sg = bid >> 7;        // 0..1
    const int db = bid & 127;       // 0..127
    const int tid = threadIdx.x;
    const int w = tid >> 6, l = tid & 63;
    const int stile = sg * 64 + w * 16;
    const int lrow = l & 15, lgrp = l >> 4;

    __shared__ __align__(16) ushort Hlds[32][40];  // [d][k], 80B rows (16B-aligned)

    floatx4 acc0 = {0.f, 0.f, 0.f, 0.f};
    floatx4 acc1 = {0.f, 0.f, 0.f, 0.f};

    const int r = tid >> 3;          // staging: k row 0..31
    const int cc = (tid & 7) * 4;    // staging: d col 0..28

    for (int kk = 0; kk < KSEL; kk += 32) {
        // stage Hsel[kk..+32][db*32..+32] transposed -> Hlds[d][k]
        uint2 v = *reinterpret_cast<const uint2*>(
            Hsel + (size_t)(kk + r) * HDIM + db * 32 + cc);
        Hlds[cc + 0][r] = (ushort)(v.x & 0xFFFFu);
        Hlds[cc + 1][r] = (ushort)(v.x >> 16);
        Hlds[cc + 2][r] = (ushort)(v.y & 0xFFFFu);
        Hlds[cc + 3][r] = (ushort)(v.y >> 16);
        __syncthreads();

        short8v a = *reinterpret_cast<const short8v*>(
            M_T + (size_t)(stile + lrow) * KSEL + kk + 8 * lgrp);
        short8v b0 = *reinterpret_cast<const short8v*>(&Hlds[lrow][8 * lgrp]);
        short8v b1 = *reinterpret_cast<const short8v*>(&Hlds[16 + lrow][8 * lgrp]);
        acc0 = __builtin_amdgcn_mfma_f32_16x16x32_bf16(a, b0, acc0, 0, 0, 0);
        acc1 = __builtin_amdgcn_mfma_f32_16x16x32_bf16(a, b1, acc1, 0, 0, 0);
        __syncthreads();
    }

    // epilogue: segment-mean + EMA + write
    #pragma unroll
    for (int reg = 0; reg < 4; reg++) {
        const int slot = stile + lgrp * 4 + reg;
        const int cnt = counts[slot];
        const float inv = (cnt > 0) ? (1.0f / (float)cnt) : 0.f;
        {
            const size_t o = (size_t)slot * HDIM + db * 32 + lrow;
            float cur = mem[o];
            out[o] = (cnt > 0) ? (0.1f * (acc0[reg] * inv) + 0.9f * cur) : cur;
        }
        {
            const size_t o = (size_t)slot * HDIM + db * 32 + 16 + lrow;
            float cur = mem[o];
            out[o] = (cnt > 0) ? (0.1f * (acc1[reg] * inv) + 0.9f * cur) : cur;
        }
    }
}

extern "C" void kernel_launch(void* const* d_in, const int* in_sizes, int n_in,
                              void* d_out, int out_size, void* d_ws, size_t ws_size,
                              hipStream_t stream) {
    const float* h    = (const float*)d_in[0];  // [8192, 4096]
    const float* attn = (const float*)d_in[1];  // [8192, 4]
    const int*   si   = (const int*)d_in[2];    // [8192, 4]
    const float* mem  = (const float*)d_in[3];  // [1, 128, 4096]
    const float* W    = (const float*)d_in[4];  // [1, 4096]
    const float* b    = (const float*)d_in[5];  // [1]
    float* out = (float*)d_out;                 // [1, 128, 4096]

    char* ws = (char*)d_ws;
    float*  imp    = (float*)(ws);              // 8192 f32
    int*    rank   = (int*)(ws + 32768);        // 8192 i32
    int*    counts = (int*)(ws + 65536);        // 128 i32
    ushort* M_T    = (ushort*)(ws + 131072);    // 128 x 2048 bf16 (512 KB)
    ushort* Hsel   = (ushort*)(ws + 2097152);   // 2048 x 4096 bf16 (16 MB)

    importance_kernel<<<T_TOK / 4, 256, 0, stream>>>(h, attn, W, b, imp, rank);
    rank_kernel<<<1024, 256, 0, stream>>>(imp, rank, counts);
    gather_kernel<<<256, 256, 0, stream>>>(h, rank, si, Hsel, M_T, counts);
    einsum_kernel<<<256, 256, 0, stream>>>(Hsel, M_T, counts, mem, out);
}

// Round 16
// 59.823 us; speedup vs baseline: 3.7152x; 1.8071x over previous
//
#include <hip/hip_runtime.h>
#include <math.h>

#define T_TOK 8192
#define HDIM 4096
#define NSLOT 128
#define KRET 4
#define TOPK 2048
#define ALPHA 0.1f
#define MAXC 2048   // hard bound: a slot appears at most once per selected token

// ---------------- Kernel 1: per-token importance (+ zero rank) ----------------
__global__ __launch_bounds__(256) void importance_kernel(
    const float* __restrict__ h, const float* __restrict__ attn,
    const float* __restrict__ W, const float* __restrict__ b,
    float* __restrict__ imp, int* __restrict__ rank)
{
    const int wid  = threadIdx.x >> 6;
    const int lane = threadIdx.x & 63;
    const int t = blockIdx.x * 4 + wid;
    const float4* hv = reinterpret_cast<const float4*>(h + (size_t)t * HDIM);
    const float4* Wv = reinterpret_cast<const float4*>(W);
    float sumsq = 0.f, dot = 0.f;
    #pragma unroll 4
    for (int i = 0; i < 16; i++) {
        float4 x = hv[lane + i * 64];
        float4 w = Wv[lane + i * 64];
        sumsq += x.x * x.x + x.y * x.y + x.z * x.z + x.w * x.w;
        dot   += x.x * w.x + x.y * w.y + x.z * w.z + x.w * w.w;
    }
    #pragma unroll
    for (int off = 32; off > 0; off >>= 1) {
        sumsq += __shfl_down(sumsq, off);
        dot   += __shfl_down(dot, off);
    }
    if (lane == 0) {
        float mag = sqrtf(sumsq);
        float ent = 0.f;
        #pragma unroll
        for (int k = 0; k < KRET; k++) {
            float a = attn[t * KRET + k];
            ent -= a * logf(a + 1e-8f);
        }
        float surprise = ent / logf(4.0f);
        float score = dot + b[0];
        float sig = 1.0f / (1.0f + expf(-score));
        imp[t] = mag * (1.0f + surprise) + sig;
        rank[t] = 0;  // zero for rank_kernel (stream-ordered, replay-safe)
    }
}

// ---------------- Kernel 2: partial rank count, 2-D grid ----------------
__global__ __launch_bounds__(256) void rank_kernel(
    const float* __restrict__ imp, int* __restrict__ rank)
{
    const int cb = blockIdx.x & 31;   // candidate block
    const int sl = blockIdx.x >> 5;   // compare slice
    __shared__ float tile[256];
    const int base = sl * 256;
    tile[threadIdx.x] = imp[base + threadIdx.x];
    __syncthreads();
    const int t = cb * 256 + threadIdx.x;
    const float mine = imp[t];
    int r = 0;
    #pragma unroll 8
    for (int i = 0; i < 256; i++) {
        float v = tile[i];
        int s = base + i;
        // jax.lax.top_k tie-break: higher value first, then lower index
        r += (v > mine) || (v == mine && s < t);
    }
    if (r) atomicAdd(&rank[t], r);
}

// ---------------- Kernel 3: per-slot CSR list, direct from rank+si ----------
// One block per slot; ordered compaction (ascending t) -> deterministic.
__global__ __launch_bounds__(256) void slotlist_kernel(
    const int* __restrict__ rank, const int* __restrict__ si,
    int* __restrict__ lists, int* __restrict__ counts)
{
    const int slot = blockIdx.x;
    const int tid = threadIdx.x;
    __shared__ int part[256];
    const int base = tid * 32;
    unsigned mask = 0;
    int local = 0;
    const int4* si4 = reinterpret_cast<const int4*>(si);
    #pragma unroll 8
    for (int j = 0; j < 32; j++) {
        const int t = base + j;
        int4 s = si4[t];
        bool sel = rank[t] < TOPK;
        bool mem = (s.x == slot) | (s.y == slot) | (s.z == slot) | (s.w == slot);
        if (sel && mem) { mask |= (1u << j); local++; }
    }
    part[tid] = local;
    __syncthreads();
    for (int off = 1; off < 256; off <<= 1) {
        int v = part[tid];
        int add = (tid >= off) ? part[tid - off] : 0;
        __syncthreads();
        part[tid] = v + add;
        __syncthreads();
    }
    int pos = part[tid] - local;  // exclusive prefix
    int* mylist = lists + (size_t)slot * MAXC;
    for (int j = 0; j < 32; j++) {
        if (mask & (1u << j)) mylist[pos++] = base + j;
    }
    if (tid == 255) counts[slot] = part[255];
}

// ---------------- Kernel 4: CSR gather + segment-mean + EMA ----------------
// XCD-locality remap: bid = g*8 + x (x = XCD via round-robin %8).
// chunk = x>>1, slot = g*2 + (x&1)  ->  each XCD serves ONE d-chunk only.
// All slot-lists advance through ascending token space in loose lockstep, so
// the per-XCD L2 working set is ~2.5 MB (fits 4 MB) and the ~4x slot
// re-reads hit L2 (34 TB/s) instead of L3. Arithmetic identical to R4.
__global__ __launch_bounds__(256) void update_kernel(
    const float* __restrict__ h, const float* __restrict__ mem,
    const int* __restrict__ lists, const int* __restrict__ counts,
    float* __restrict__ out)
{
    const int x = blockIdx.x & 7;
    const int g = blockIdx.x >> 3;
    const int chunk = x >> 1;           // 0..3
    const int slot  = g * 2 + (x & 1);  // 0..127
    const int cnt = counts[slot];
    __shared__ int s_list[MAXC];
    for (int i = threadIdx.x; i < cnt; i += 256)
        s_list[i] = lists[(size_t)slot * MAXC + i];
    __syncthreads();

    const int dbase = chunk * 1024 + threadIdx.x * 4;
    float4 acc = make_float4(0.f, 0.f, 0.f, 0.f);
    int i = 0;
    for (; i + 4 <= cnt; i += 4) {
        int t0 = s_list[i], t1 = s_list[i + 1];
        int t2 = s_list[i + 2], t3 = s_list[i + 3];
        float4 x0 = *reinterpret_cast<const float4*>(h + (size_t)t0 * HDIM + dbase);
        float4 x1 = *reinterpret_cast<const float4*>(h + (size_t)t1 * HDIM + dbase);
        float4 x2 = *reinterpret_cast<const float4*>(h + (size_t)t2 * HDIM + dbase);
        float4 x3 = *reinterpret_cast<const float4*>(h + (size_t)t3 * HDIM + dbase);
        acc.x += x0.x + x1.x + x2.x + x3.x;
        acc.y += x0.y + x1.y + x2.y + x3.y;
        acc.z += x0.z + x1.z + x2.z + x3.z;
        acc.w += x0.w + x1.w + x2.w + x3.w;
    }
    for (; i < cnt; i++) {
        int t0 = s_list[i];
        float4 x0 = *reinterpret_cast<const float4*>(h + (size_t)t0 * HDIM + dbase);
        acc.x += x0.x; acc.y += x0.y; acc.z += x0.z; acc.w += x0.w;
    }

    const size_t o = (size_t)slot * HDIM + dbase;
    float4 cur = *reinterpret_cast<const float4*>(mem + o);
    float4 r;
    if (cnt > 0) {
        float inv = 1.0f / (float)cnt;
        r.x = ALPHA * (acc.x * inv) + (1.f - ALPHA) * cur.x;
        r.y = ALPHA * (acc.y * inv) + (1.f - ALPHA) * cur.y;
        r.z = ALPHA * (acc.z * inv) + (1.f - ALPHA) * cur.z;
        r.w = ALPHA * (acc.w * inv) + (1.f - ALPHA) * cur.w;
    } else {
        r = cur;
    }
    *reinterpret_cast<float4*>(out + o) = r;
}

extern "C" void kernel_launch(void* const* d_in, const int* in_sizes, int n_in,
                              void* d_out, int out_size, void* d_ws, size_t ws_size,
                              hipStream_t stream) {
    const float* h    = (const float*)d_in[0];  // [8192, 4096]
    const float* attn = (const float*)d_in[1];  // [8192, 4]
    const int*   si   = (const int*)d_in[2];    // [8192, 4]
    const float* mem  = (const float*)d_in[3];  // [1, 128, 4096]
    const float* W    = (const float*)d_in[4];  // [1, 4096]
    const float* b    = (const float*)d_in[5];  // [1]
    float* out = (float*)d_out;                 // [1, 128, 4096]

    char* ws = (char*)d_ws;
    float* imp    = (float*)(ws);            // 8192 f32
    int*   rank   = (int*)(ws + 32768);      // 8192 i32
    int*   counts = (int*)(ws + 65536);      // 128 i32
    int*   lists  = (int*)(ws + 131072);     // 128 x 2048 i32 (1 MB)

    importance_kernel<<<T_TOK / 4, 256, 0, stream>>>(h, attn, W, b, imp, rank);
    rank_kernel<<<1024, 256, 0, stream>>>(imp, rank);
    slotlist_kernel<<<NSLOT, 256, 0, stream>>>(rank, si, lists, counts);
    update_kernel<<<NSLOT * 4, 256, 0, stream>>>(h, mem, lists, counts, out);
}